// Round 13
// baseline (233.050 us; speedup 1.0000x reference)
//
#include <hip/hip_runtime.h>
#include <math.h>

#define N_NODES 50000
#define N_EDGES 800000
#define N_CAND  100000
#define D       128
#define BN_EPS  1e-5f
#define SLOPE   0.01f

// tiled-binning CSR build
#define NB2     196
#define TILE    4096
#define NTILE   196
#define BCAP    4736

typedef __attribute__((ext_vector_type(8))) short bf16x8;
typedef __attribute__((ext_vector_type(4))) float f32x4;

__device__ __forceinline__ float lrelu(float x){ return x >= 0.f ? x : SLOPE * x; }

__device__ __forceinline__ unsigned short f2bf_rn(float f){
  unsigned int u = __float_as_uint(f);
  unsigned int r = u + 0x7FFFu + ((u >> 16) & 1u);
  return (unsigned short)(r >> 16);
}
__device__ __forceinline__ float bf2f(unsigned short h){
  return __uint_as_float(((unsigned int)h) << 16);
}
__device__ __forceinline__ float bfu(unsigned u){ return __uint_as_float(u << 16); }
__device__ __forceinline__ float bfh(unsigned u){ return __uint_as_float(u & 0xffff0000u); }
__device__ __forceinline__ float4 bf4f(ushort4 u){
  return make_float4(__uint_as_float((unsigned)u.x << 16),
                     __uint_as_float((unsigned)u.y << 16),
                     __uint_as_float((unsigned)u.z << 16),
                     __uint_as_float((unsigned)u.w << 16));
}

__device__ __forceinline__ unsigned pk_bf16(float a, float b){
  unsigned r;
  asm("v_cvt_pk_bf16_f32 %0, %1, %2" : "=v"(r) : "v"(a), "v"(b));
  return r;
}
__device__ __forceinline__ void split2(float a, float b, unsigned &h, unsigned &l){
  h = pk_bf16(a, b);
  float ra = a - __uint_as_float(h << 16);
  float rb = b - __uint_as_float(h & 0xffff0000u);
  l = pk_bf16(ra, rb);
}

// ---------------- CSR build: LDS-staged tiled binning ----------------
__global__ __launch_bounds__(256) void k_bin(const int* __restrict__ src, const int* __restrict__ dst,
                                             int* __restrict__ gcnt, unsigned* __restrict__ ebin, int E){
  __shared__ unsigned stage[TILE];
  __shared__ int hist[256], lscan[256], lex[256], lcur[256], gbase[256];
  __shared__ int stot;
  int t = threadIdx.x;
  int e0 = blockIdx.x * TILE;

  hist[t] = 0;
  __syncthreads();

  unsigned pk[16]; int bk[16]; bool ok[16];
  #pragma unroll
  for (int j = 0; j < 16; ++j){
    int i = e0 + j * 256 + t;
    ok[j] = (i < E);
    if (ok[j]){
      int d = dst[i];
      pk[j] = ((unsigned)d << 16) | (unsigned)src[i];
      bk[j] = d >> 8;
      atomicAdd(&hist[bk[j]], 1);
    }
  }
  __syncthreads();

  lscan[t] = hist[t];
  __syncthreads();
  for (int off = 1; off < 256; off <<= 1){
    int v = (t >= off) ? lscan[t - off] : 0;
    __syncthreads();
    lscan[t] += v;
    __syncthreads();
  }
  int ex = lscan[t] - hist[t];
  lex[t]  = ex;
  lcur[t] = ex;
  if (t < NB2) gbase[t] = hist[t] ? atomicAdd(&gcnt[t], hist[t]) : 0;
  if (t == 255) stot = lscan[255];
  __syncthreads();

  #pragma unroll
  for (int j = 0; j < 16; ++j){
    if (ok[j]){
      int p = atomicAdd(&lcur[bk[j]], 1);
      stage[p] = pk[j];
    }
  }
  __syncthreads();

  int tot = stot;
  for (int i = t; i < tot; i += 256){
    unsigned e = stage[i];
    int b = (int)(e >> 24);
    ebin[(size_t)b * BCAP + gbase[b] + (i - lex[b])] = e;
  }
}

__global__ __launch_bounds__(256) void k_bscan2(const int* __restrict__ gcnt, int* __restrict__ bbase,
                                                int* __restrict__ rowptr){
  __shared__ int sd[256];
  int t = threadIdx.x;
  int v = (t < NB2) ? gcnt[t] : 0;
  sd[t] = v; __syncthreads();
  for (int off = 1; off < 256; off <<= 1){
    int a = (t >= off) ? sd[t - off] : 0;
    __syncthreads();
    sd[t] += a; __syncthreads();
  }
  if (t < NB2) bbase[t] = sd[t] - v;
  if (t == NB2 - 1) rowptr[N_NODES] = sd[t];
}

__global__ __launch_bounds__(256) void k_bfin(const int* __restrict__ gcnt, const int* __restrict__ bbase,
                                              const unsigned* __restrict__ ebin,
                                              unsigned short* __restrict__ eid16,
                                              int* __restrict__ rowptr, int n){
  __shared__ int hist[256], lb[256], lcur[256];
  int t = threadIdx.x, b = blockIdx.x;
  int cb   = gcnt[b];
  int base = bbase[b];
  const unsigned* eb = &ebin[(size_t)b * BCAP];
  hist[t] = 0;
  __syncthreads();
  for (int idx = t; idx < cb; idx += 256) atomicAdd(&hist[(eb[idx] >> 16) & 255], 1);
  __syncthreads();
  lb[t] = hist[t];
  __syncthreads();
  for (int off = 1; off < 256; off <<= 1){
    int v = (t >= off) ? lb[t - off] : 0;
    __syncthreads();
    lb[t] += v; __syncthreads();
  }
  int ex = lb[t] - hist[t];
  lcur[t] = ex;
  int node = (b << 8) + t;
  if (node < n) rowptr[node] = base + ex;
  __syncthreads();
  for (int idx = t; idx < cb; idx += 256){
    unsigned e = eb[idx];
    int p = atomicAdd(&lcur[(e >> 16) & 255], 1);
    eid16[base + p] = (unsigned short)(e & 0xffffu);
  }
}

// ---------------- fused prep: all weight/input conversions in ONE kernel ----------------
__global__ __launch_bounds__(256) void k_prep(
    const float* __restrict__ ws0, const float* __restrict__ wn0,
    const float* __restrict__ ws1, const float* __restrict__ wn1,
    const float* __restrict__ mw0, const float* __restrict__ mw1,
    const float* __restrict__ X,
    unsigned short* __restrict__ bth0, unsigned short* __restrict__ btl0,
    unsigned short* __restrict__ bth1, unsigned short* __restrict__ btl1,
    unsigned short* __restrict__ w1th, unsigned short* __restrict__ w1tl,
    unsigned short* __restrict__ w0cth, unsigned short* __restrict__ w0ctl,
    unsigned short* __restrict__ XH, unsigned short* __restrict__ XL)
{
  int b = blockIdx.x, t = threadIdx.x;
  if (b < 256){
    int col = b & 127;
    const float* wsp = (b < 128) ? ws0 : ws1;
    const float* wnp = (b < 128) ? wn0 : wn1;
    unsigned short* th = (b < 128) ? bth0 : bth1;
    unsigned short* tl = (b < 128) ? btl0 : btl1;
    float v = (t < 128) ? wsp[t * D + col] : wnp[(t - 128) * D + col];
    unsigned short hi = f2bf_rn(v);
    th[col * 256 + t] = hi;
    tl[col * 256 + t] = f2bf_rn(v - bf2f(hi));
  } else if (b < 320){
    if (t < 64){
      int col = b - 256;
      float v = mw1[t * 64 + col];
      unsigned short hi = f2bf_rn(v);
      w1th[col * 64 + t] = hi;
      w1tl[col * 64 + t] = f2bf_rn(v - bf2f(hi));
    }
  } else if (b < 448){
    if (t < 128){
      int col = b - 320;
      float v = (col < 64) ? mw0[t * 64 + col] : mw0[(128 + t) * 64 + (col - 64)];
      unsigned short hi = f2bf_rn(v);
      w0cth[col * 128 + t] = hi;
      w0ctl[col * 128 + t] = f2bf_rn(v - bf2f(hi));
    }
  } else {
    int i = (b - 448) * 256 + t;            // 8 floats per thread
    if (i < N_NODES * D / 8){
      const float4* xp = reinterpret_cast<const float4*>(&X[(size_t)i * 8]);
      float4 v0 = xp[0], v1 = xp[1];
      uint4 h, l;
      split2(v0.x, v0.y, h.x, l.x);
      split2(v0.z, v0.w, h.y, l.y);
      split2(v1.x, v1.y, h.z, l.z);
      split2(v1.z, v1.w, h.w, l.w);
      *reinterpret_cast<uint4*>(&XH[(size_t)i * 8]) = h;
      *reinterpret_cast<uint4*>(&XL[(size_t)i * 8]) = l;
    }
  }
}

// ---------------- mean aggregation: D-quarter cache-blocked bf16 gather ----------------
// 32 nodes/block (8 lanes x 8B = one 64B line per edge per quarter), grid
// 1563 blocks = fully co-resident, so all blocks sweep the 4 D-quarters
// roughly in phase: per-quarter gather table = 3.2MB < 4MB per-XCD L2 ->
// the random gather becomes L2-resident instead of L3/HBM-latency-bound.
// Quarter loop MUST stay sequential (unroll 1) or the locality is lost.
// Arithmetic is bit-identical to the previous full-row version.
__global__ __launch_bounds__(256) void k_agg_q(const unsigned short* __restrict__ XB,
                                               const int* __restrict__ rowptr, const unsigned short* __restrict__ eid,
                                               unsigned short* __restrict__ AGH, unsigned short* __restrict__ AGL,
                                               int n){
  int g  = blockIdx.x * 32 + (threadIdx.x >> 3);   // node
  int li = threadIdx.x & 7;                        // 4-col chunk within quarter
  if (g >= n) return;
  int e0 = rowptr[g], e1 = rowptr[g + 1];
  float sc = 1.f / fmaxf((float)(e1 - e0), 1.f);

  #pragma unroll 1
  for (int q = 0; q < 4; ++q){
    int off = q * 32 + li * 4;
    float4 a0 = make_float4(0.f,0.f,0.f,0.f);
    float4 a1 = make_float4(0.f,0.f,0.f,0.f);
    float4 a2 = make_float4(0.f,0.f,0.f,0.f);
    float4 a3 = make_float4(0.f,0.f,0.f,0.f);
    int e = e0;
    for (; e + 4 <= e1; e += 4){
      int s0 = eid[e], s1 = eid[e + 1], s2 = eid[e + 2], s3 = eid[e + 3];
      ushort4 u0 = *reinterpret_cast<const ushort4*>(&XB[(size_t)s0 * D + off]);
      ushort4 u1 = *reinterpret_cast<const ushort4*>(&XB[(size_t)s1 * D + off]);
      ushort4 u2 = *reinterpret_cast<const ushort4*>(&XB[(size_t)s2 * D + off]);
      ushort4 u3 = *reinterpret_cast<const ushort4*>(&XB[(size_t)s3 * D + off]);
      float4 f0 = bf4f(u0), f1 = bf4f(u1), f2 = bf4f(u2), f3 = bf4f(u3);
      a0.x += f0.x; a0.y += f0.y; a0.z += f0.z; a0.w += f0.w;
      a1.x += f1.x; a1.y += f1.y; a1.z += f1.z; a1.w += f1.w;
      a2.x += f2.x; a2.y += f2.y; a2.z += f2.z; a2.w += f2.w;
      a3.x += f3.x; a3.y += f3.y; a3.z += f3.z; a3.w += f3.w;
    }
    for (; e < e1; ++e){
      int s0 = eid[e];
      ushort4 u0 = *reinterpret_cast<const ushort4*>(&XB[(size_t)s0 * D + off]);
      float4 f0 = bf4f(u0);
      a0.x += f0.x; a0.y += f0.y; a0.z += f0.z; a0.w += f0.w;
    }
    float ox = (a0.x + a1.x + a2.x + a3.x) * sc;
    float oy = (a0.y + a1.y + a2.y + a3.y) * sc;
    float oz = (a0.z + a1.z + a2.z + a3.z) * sc;
    float ow = (a0.w + a1.w + a2.w + a3.w) * sc;
    uint2 h, lo_;
    split2(ox, oy, h.x, lo_.x);
    split2(oz, ow, h.y, lo_.y);
    *reinterpret_cast<uint2*>(&AGH[(size_t)g * D + off]) = h;
    *reinterpret_cast<uint2*>(&AGL[(size_t)g * D + off]) = lo_;
  }
}

// ---------------- SAGE layer via split-bf16 MFMA (all-pre-split inputs) ----------------
__global__ __launch_bounds__(256) void k_sage_mfma(
    const unsigned short* __restrict__ A0H, const unsigned short* __restrict__ A0L,
    const unsigned short* __restrict__ A1H, const unsigned short* __restrict__ A1L,
    const unsigned short* __restrict__ BTH, const unsigned short* __restrict__ BTL,
    const float* __restrict__ Bb, const float* __restrict__ GM, const float* __restrict__ BT,
    const float* __restrict__ RM, const float* __restrict__ RV,
    unsigned short* __restrict__ HBH, unsigned short* __restrict__ HBL,
    int n, int donan)
{
  __shared__ unsigned short Ah[64 * 40];
  __shared__ unsigned short Al[64 * 40];
  __shared__ unsigned short Bh[128 * 40];
  __shared__ unsigned short Bl[128 * 40];

  int t  = threadIdx.x;
  int l  = t & 63;
  int wv = t >> 6;
  int lm = l & 15;
  int lk = l >> 4;
  int node0 = blockIdx.x * 64;

  f32x4 acc[8];
  #pragma unroll
  for (int f = 0; f < 8; ++f) acc[f] = (f32x4){0.f, 0.f, 0.f, 0.f};

  for (int step = 0; step < 8; ++step){
    int k0 = step * 32;
    const unsigned short* srcH = (step < 4) ? A0H : A1H;
    const unsigned short* srcL = (step < 4) ? A0L : A1L;
    int koff = (step < 4) ? k0 : (k0 - 128);

    __syncthreads();
    {
      int row = t >> 2, q = t & 3;
      int node = min(node0 + row, n - 1);
      *reinterpret_cast<uint4*>(&Ah[row * 40 + q * 8]) =
          *reinterpret_cast<const uint4*>(&srcH[(size_t)node * D + koff + q * 8]);
      *reinterpret_cast<uint4*>(&Al[row * 40 + q * 8]) =
          *reinterpret_cast<const uint4*>(&srcL[(size_t)node * D + koff + q * 8]);
    }
    #pragma unroll
    for (int i = 0; i < 2; ++i){
      int c   = t + i * 256;
      int col = c >> 2, q = c & 3;
      *reinterpret_cast<uint4*>(&Bh[col * 40 + q * 8]) =
          *reinterpret_cast<const uint4*>(&BTH[col * 256 + k0 + q * 8]);
      *reinterpret_cast<uint4*>(&Bl[col * 40 + q * 8]) =
          *reinterpret_cast<const uint4*>(&BTL[col * 256 + k0 + q * 8]);
    }
    __syncthreads();

    bf16x8 afh = *reinterpret_cast<const bf16x8*>(&Ah[(wv * 16 + lm) * 40 + lk * 8]);
    bf16x8 afl = *reinterpret_cast<const bf16x8*>(&Al[(wv * 16 + lm) * 40 + lk * 8]);
    #pragma unroll
    for (int f = 0; f < 8; ++f){
      bf16x8 bfh = *reinterpret_cast<const bf16x8*>(&Bh[(f * 16 + lm) * 40 + lk * 8]);
      bf16x8 bfl = *reinterpret_cast<const bf16x8*>(&Bl[(f * 16 + lm) * 40 + lk * 8]);
      acc[f] = __builtin_amdgcn_mfma_f32_16x16x32_bf16(afh, bfh, acc[f], 0, 0, 0);
      acc[f] = __builtin_amdgcn_mfma_f32_16x16x32_bf16(afl, bfh, acc[f], 0, 0, 0);
      acc[f] = __builtin_amdgcn_mfma_f32_16x16x32_bf16(afh, bfl, acc[f], 0, 0, 0);
    }
  }

  #pragma unroll
  for (int f = 0; f < 8; ++f){
    int col = f * 16 + lm;
    float s  = GM[col] * rsqrtf(RV[col] + BN_EPS);
    float cj = (Bb[col] - RM[col]) * s + BT[col];
    #pragma unroll
    for (int r = 0; r < 4; ++r){
      int node = node0 + wv * 16 + lk * 4 + r;
      if (node < n){
        float v = lrelu(acc[f][r] * s + cj);
        if (donan && (v != v)) v = 1e-14f;
        unsigned short h16 = f2bf_rn(v);
        HBH[(size_t)node * D + col] = h16;
        HBL[(size_t)node * D + col] = f2bf_rn(v - bf2f(h16));
      }
    }
  }
}

// ---------------- P = h1 @ [W0u | W0v]  (dense GEMM, pre-split in/out) ----------------
__global__ __launch_bounds__(256) void k_pgemm(
    const unsigned short* __restrict__ HH, const unsigned short* __restrict__ HL,
    const unsigned short* __restrict__ WCH, const unsigned short* __restrict__ WCL,
    unsigned short* __restrict__ PH, unsigned short* __restrict__ PL, int n)
{
  __shared__ unsigned short Ah[64 * 40];
  __shared__ unsigned short Al[64 * 40];
  __shared__ unsigned short Bh[128 * 40];
  __shared__ unsigned short Bl[128 * 40];

  int t  = threadIdx.x;
  int l  = t & 63;
  int wv = t >> 6;
  int lm = l & 15;
  int lk = l >> 4;
  int node0 = blockIdx.x * 64;

  f32x4 acc[8];
  #pragma unroll
  for (int f = 0; f < 8; ++f) acc[f] = (f32x4){0.f, 0.f, 0.f, 0.f};

  for (int step = 0; step < 4; ++step){
    int k0 = step * 32;
    __syncthreads();
    {
      int row = t >> 2, q = t & 3;
      int node = min(node0 + row, n - 1);
      *reinterpret_cast<uint4*>(&Ah[row * 40 + q * 8]) =
          *reinterpret_cast<const uint4*>(&HH[(size_t)node * D + k0 + q * 8]);
      *reinterpret_cast<uint4*>(&Al[row * 40 + q * 8]) =
          *reinterpret_cast<const uint4*>(&HL[(size_t)node * D + k0 + q * 8]);
    }
    #pragma unroll
    for (int i = 0; i < 2; ++i){
      int c = t + i * 256;
      int col = c >> 2, q = c & 3;
      *reinterpret_cast<uint4*>(&Bh[col * 40 + q * 8]) =
          *reinterpret_cast<const uint4*>(&WCH[col * 128 + k0 + q * 8]);
      *reinterpret_cast<uint4*>(&Bl[col * 40 + q * 8]) =
          *reinterpret_cast<const uint4*>(&WCL[col * 128 + k0 + q * 8]);
    }
    __syncthreads();

    bf16x8 afh = *reinterpret_cast<const bf16x8*>(&Ah[(wv * 16 + lm) * 40 + lk * 8]);
    bf16x8 afl = *reinterpret_cast<const bf16x8*>(&Al[(wv * 16 + lm) * 40 + lk * 8]);
    #pragma unroll
    for (int f = 0; f < 8; ++f){
      bf16x8 bfh = *reinterpret_cast<const bf16x8*>(&Bh[(f * 16 + lm) * 40 + lk * 8]);
      bf16x8 bfl = *reinterpret_cast<const bf16x8*>(&Bl[(f * 16 + lm) * 40 + lk * 8]);
      acc[f] = __builtin_amdgcn_mfma_f32_16x16x32_bf16(afh, bfh, acc[f], 0, 0, 0);
      acc[f] = __builtin_amdgcn_mfma_f32_16x16x32_bf16(afl, bfh, acc[f], 0, 0, 0);
      acc[f] = __builtin_amdgcn_mfma_f32_16x16x32_bf16(afh, bfl, acc[f], 0, 0, 0);
    }
  }

  #pragma unroll
  for (int f = 0; f < 8; ++f){
    int col = f * 16 + lm;
    #pragma unroll
    for (int r = 0; r < 4; ++r){
      int node = node0 + wv * 16 + lk * 4 + r;
      if (node < n){
        float v = acc[f][r];
        unsigned short h16 = f2bf_rn(v);
        PH[(size_t)node * D + col] = h16;
        PL[(size_t)node * D + col] = f2bf_rn(v - bf2f(h16));
      }
    }
  }
}

__device__ __forceinline__ void proc2(unsigned uh, unsigned ul, unsigned vh, unsigned vl,
                                      float wfa, float wfb, float b0a, float b0b, float cfv,
                                      unsigned &ho, unsigned &lo_){
  float z0 = lrelu(bfu(uh) + bfu(ul) + bfu(vh) + bfu(vl) + cfv * wfa + b0a);
  float z1 = lrelu(bfh(uh) + bfh(ul) + bfh(vh) + bfh(vl) + cfv * wfb + b0b);
  split2(z0, z1, ho, lo_);
}

// ---------------- candidate MLP tail: gather P + L2 + L3 ----------------
__global__ __launch_bounds__(256) void k_mlp2(
    const unsigned short* __restrict__ PH, const unsigned short* __restrict__ PL,
    const int* __restrict__ cu, const int* __restrict__ cv, const float* __restrict__ cf,
    const float* __restrict__ mw0, const float* __restrict__ mb0,
    const unsigned short* __restrict__ W1H, const unsigned short* __restrict__ W1L,
    const float* __restrict__ mb1, const float* __restrict__ mw2, const float* __restrict__ mb2,
    float* __restrict__ y, int C)
{
  __shared__ unsigned short zh[4][32 * 72];
  __shared__ unsigned short zl[4][32 * 72];
  __shared__ float bw[64], ww[64];

  int t = threadIdx.x;
  int wv = t >> 6, l = t & 63, lm = l & 15, lk = l >> 4;
  int cl = l & 31, hsel = l >> 5;
  int candbase = blockIdx.x * 128 + wv * 32;

  if (t < 64){ bw[t] = mb0[t]; ww[t] = mw0[256 * 64 + t]; }
  __syncthreads();

  int cc = min(candbase + cl, C - 1);
  int nu = cu[cc], nv = cv[cc];
  float cfv = cf[cc];

  const uint4* puh = reinterpret_cast<const uint4*>(&PH[(size_t)nu * D + hsel * 32]);
  const uint4* pul = reinterpret_cast<const uint4*>(&PL[(size_t)nu * D + hsel * 32]);
  const uint4* pvh = reinterpret_cast<const uint4*>(&PH[(size_t)nv * D + 64 + hsel * 32]);
  const uint4* pvl = reinterpret_cast<const uint4*>(&PL[(size_t)nv * D + 64 + hsel * 32]);
  uint4 uh0 = puh[0], uh1 = puh[1], uh2 = puh[2], uh3 = puh[3];
  uint4 ul0 = pul[0], ul1 = pul[1], ul2 = pul[2], ul3 = pul[3];
  uint4 vh0 = pvh[0], vh1 = pvh[1], vh2 = pvh[2], vh3 = pvh[3];
  uint4 vl0 = pvl[0], vl1 = pvl[1], vl2 = pvl[2], vl3 = pvl[3];

  int colb = hsel * 32;
  unsigned short* zhr = &zh[wv][cl * 72];
  unsigned short* zlr = &zl[wv][cl * 72];
  #define PROC_W(UH, UL, VH, VL, CO) { \
    unsigned ho, lo_; \
    proc2(UH, UL, VH, VL, ww[colb + (CO)], ww[colb + (CO) + 1], bw[colb + (CO)], bw[colb + (CO) + 1], cfv, ho, lo_); \
    *reinterpret_cast<unsigned*>(&zhr[colb + (CO)]) = ho; \
    *reinterpret_cast<unsigned*>(&zlr[colb + (CO)]) = lo_; }
  PROC_W(uh0.x, ul0.x, vh0.x, vl0.x, 0)  PROC_W(uh0.y, ul0.y, vh0.y, vl0.y, 2)
  PROC_W(uh0.z, ul0.z, vh0.z, vl0.z, 4)  PROC_W(uh0.w, ul0.w, vh0.w, vl0.w, 6)
  PROC_W(uh1.x, ul1.x, vh1.x, vl1.x, 8)  PROC_W(uh1.y, ul1.y, vh1.y, vl1.y, 10)
  PROC_W(uh1.z, ul1.z, vh1.z, vl1.z, 12) PROC_W(uh1.w, ul1.w, vh1.w, vl1.w, 14)
  PROC_W(uh2.x, ul2.x, vh2.x, vl2.x, 16) PROC_W(uh2.y, ul2.y, vh2.y, vl2.y, 18)
  PROC_W(uh2.z, ul2.z, vh2.z, vl2.z, 20) PROC_W(uh2.w, ul2.w, vh2.w, vl2.w, 22)
  PROC_W(uh3.x, ul3.x, vh3.x, vl3.x, 24) PROC_W(uh3.y, ul3.y, vh3.y, vl3.y, 26)
  PROC_W(uh3.z, ul3.z, vh3.z, vl3.z, 28) PROC_W(uh3.w, ul3.w, vh3.w, vl3.w, 30)
  #undef PROC_W

  int kbase = lk * 8;
  f32x4 a2[2][4];
  #pragma unroll
  for (int m = 0; m < 2; ++m)
    #pragma unroll
    for (int f = 0; f < 4; ++f) a2[m][f] = (f32x4){0.f, 0.f, 0.f, 0.f};

  #pragma unroll
  for (int s2 = 0; s2 < 2; ++s2){
    int kk = s2 * 32 + kbase;
    bf16x8 azh0 = *reinterpret_cast<const bf16x8*>(&zh[wv][(0 * 16 + lm) * 72 + kk]);
    bf16x8 azl0 = *reinterpret_cast<const bf16x8*>(&zl[wv][(0 * 16 + lm) * 72 + kk]);
    bf16x8 azh1 = *reinterpret_cast<const bf16x8*>(&zh[wv][(1 * 16 + lm) * 72 + kk]);
    bf16x8 azl1 = *reinterpret_cast<const bf16x8*>(&zl[wv][(1 * 16 + lm) * 72 + kk]);
    #pragma unroll
    for (int f = 0; f < 4; ++f){
      int col = f * 16 + lm;
      bf16x8 bh = *reinterpret_cast<const bf16x8*>(&W1H[(size_t)col * 64 + kk]);
      bf16x8 bl = *reinterpret_cast<const bf16x8*>(&W1L[(size_t)col * 64 + kk]);
      a2[0][f] = __builtin_amdgcn_mfma_f32_16x16x32_bf16(azh0, bh, a2[0][f], 0, 0, 0);
      a2[0][f] = __builtin_amdgcn_mfma_f32_16x16x32_bf16(azl0, bh, a2[0][f], 0, 0, 0);
      a2[0][f] = __builtin_amdgcn_mfma_f32_16x16x32_bf16(azh0, bl, a2[0][f], 0, 0, 0);
      a2[1][f] = __builtin_amdgcn_mfma_f32_16x16x32_bf16(azh1, bh, a2[1][f], 0, 0, 0);
      a2[1][f] = __builtin_amdgcn_mfma_f32_16x16x32_bf16(azl1, bh, a2[1][f], 0, 0, 0);
      a2[1][f] = __builtin_amdgcn_mfma_f32_16x16x32_bf16(azh1, bl, a2[1][f], 0, 0, 0);
    }
  }

  float p00 = 0.f, p01 = 0.f, p02 = 0.f, p03 = 0.f;
  float p10 = 0.f, p11 = 0.f, p12 = 0.f, p13 = 0.f;
  #pragma unroll
  for (int f = 0; f < 4; ++f){
    int col = f * 16 + lm;
    float b1v = mb1[col];
    float w2v = mw2[col];
    p00 = fmaf(lrelu(a2[0][f][0] + b1v), w2v, p00);
    p01 = fmaf(lrelu(a2[0][f][1] + b1v), w2v, p01);
    p02 = fmaf(lrelu(a2[0][f][2] + b1v), w2v, p02);
    p03 = fmaf(lrelu(a2[0][f][3] + b1v), w2v, p03);
    p10 = fmaf(lrelu(a2[1][f][0] + b1v), w2v, p10);
    p11 = fmaf(lrelu(a2[1][f][1] + b1v), w2v, p11);
    p12 = fmaf(lrelu(a2[1][f][2] + b1v), w2v, p12);
    p13 = fmaf(lrelu(a2[1][f][3] + b1v), w2v, p13);
  }
  #pragma unroll
  for (int off = 1; off < 16; off <<= 1){
    p00 += __shfl_xor(p00, off); p01 += __shfl_xor(p01, off);
    p02 += __shfl_xor(p02, off); p03 += __shfl_xor(p03, off);
    p10 += __shfl_xor(p10, off); p11 += __shfl_xor(p11, off);
    p12 += __shfl_xor(p12, off); p13 += __shfl_xor(p13, off);
  }
  if (lm == 0){
    float b2 = mb2[0];
    int base0 = candbase + lk * 4;
    int base1 = candbase + 16 + lk * 4;
    if (base0 + 0 < C) y[base0 + 0] = p00 + b2;
    if (base0 + 1 < C) y[base0 + 1] = p01 + b2;
    if (base0 + 2 < C) y[base0 + 2] = p02 + b2;
    if (base0 + 3 < C) y[base0 + 3] = p03 + b2;
    if (base1 + 0 < C) y[base1 + 0] = p10 + b2;
    if (base1 + 1 < C) y[base1 + 1] = p11 + b2;
    if (base1 + 2 < C) y[base1 + 2] = p12 + b2;
    if (base1 + 3 < C) y[base1 + 3] = p13 + b2;
  }
}

// ---------------- softmax over C logits ----------------
__global__ __launch_bounds__(256) void k_red1(const float* __restrict__ y,
                                              float* __restrict__ bmax, float* __restrict__ bsum, int C){
  __shared__ float sm[4];
  __shared__ float ss[4];
  int t = threadIdx.x;
  float m = -3.4e38f;
  for (int i = blockIdx.x * 256 + t; i < C; i += gridDim.x * 256) m = fmaxf(m, y[i]);
  for (int o = 32; o; o >>= 1) m = fmaxf(m, __shfl_xor(m, o));
  if ((t & 63) == 0) sm[t >> 6] = m;
  __syncthreads();
  float bm = fmaxf(fmaxf(sm[0], sm[1]), fmaxf(sm[2], sm[3]));
  float s = 0.f;
  for (int i = blockIdx.x * 256 + t; i < C; i += gridDim.x * 256) s += expf(y[i] - bm);
  for (int o = 32; o; o >>= 1) s += __shfl_xor(s, o);
  if ((t & 63) == 0) ss[t >> 6] = s;
  __syncthreads();
  if (t == 0){ bmax[blockIdx.x] = bm; bsum[blockIdx.x] = ss[0] + ss[1] + ss[2] + ss[3]; }
}

__global__ __launch_bounds__(256) void k_red2(const float* __restrict__ bmax, const float* __restrict__ bsum,
                                              float* __restrict__ g, int nb){
  __shared__ float sm[4];
  __shared__ float ss[4];
  int t = threadIdx.x;
  float m0 = (t < nb) ? bmax[t] : -3.4e38f;
  float m = m0;
  for (int o = 32; o; o >>= 1) m = fmaxf(m, __shfl_xor(m, o));
  if ((t & 63) == 0) sm[t >> 6] = m;
  __syncthreads();
  float gm = fmaxf(fmaxf(sm[0], sm[1]), fmaxf(sm[2], sm[3]));
  float s = (t < nb) ? bsum[t] * expf(m0 - gm) : 0.f;
  for (int o = 32; o; o >>= 1) s += __shfl_xor(s, o);
  if ((t & 63) == 0) ss[t >> 6] = s;
  __syncthreads();
  if (t == 0){ g[0] = gm; g[1] = 1.f / (ss[0] + ss[1] + ss[2] + ss[3]); }
}

__global__ __launch_bounds__(256) void k_red3(const float* __restrict__ y, const float* __restrict__ g,
                                              float* __restrict__ out, int C){
  int i = blockIdx.x * 256 + threadIdx.x;
  if (i < C) out[i] = expf(y[i] - g[0]) * g[1];
}

extern "C" void kernel_launch(void* const* d_in, const int* in_sizes, int n_in,
                              void* d_out, int out_size, void* d_ws, size_t ws_size,
                              hipStream_t stream)
{
  const float* x   = (const float*)d_in[0];
  const int*   src = (const int*)  d_in[1];
  const int*   dst = (const int*)  d_in[2];
  const int*   cu  = (const int*)  d_in[3];
  const int*   cv  = (const int*)  d_in[4];
  const float* cf  = (const float*)d_in[5];
  const float* ws0 = (const float*)d_in[6];
  const float* wn0 = (const float*)d_in[7];
  const float* b0  = (const float*)d_in[8];
  const float* g0  = (const float*)d_in[9];
  const float* be0 = (const float*)d_in[10];
  const float* rm0 = (const float*)d_in[11];
  const float* rv0 = (const float*)d_in[12];
  const float* ws1 = (const float*)d_in[13];
  const float* wn1 = (const float*)d_in[14];
  const float* b1  = (const float*)d_in[15];
  const float* g1  = (const float*)d_in[16];
  const float* be1 = (const float*)d_in[17];
  const float* rm1 = (const float*)d_in[18];
  const float* rv1 = (const float*)d_in[19];
  const float* mw0 = (const float*)d_in[20];
  const float* mb0 = (const float*)d_in[21];
  const float* mw1 = (const float*)d_in[22];
  const float* mb1 = (const float*)d_in[23];
  const float* mw2 = (const float*)d_in[24];
  const float* mb2 = (const float*)d_in[25];

  float* out = (float*)d_out;   // [C] y then [C] softmax

  char* w = (char*)d_ws;
  char* regA = w; w += (size_t)N_NODES * D * 4;   // agh/agl -> later ph/pl
  char* regB = w; w += (size_t)N_NODES * D * 4;   // ebin -> hb0h/hb0l
  char* regC = w; w += (size_t)N_NODES * D * 4;   // xh/xl -> hb1h/hb1l
  int* cnt     = (int*)w;   w += (size_t)N_NODES * 4;          // -> SAGE weights L0
  int* rowptr  = (int*)w;   w += (size_t)(N_NODES + 1) * 4;
  int* cur     = (int*)w;   w += (size_t)N_NODES * 4;          // -> SAGE weights L1
  int* eid     = (int*)w;   w += (size_t)N_EDGES * 4;          // holds eid16
  int* gcnt    = (int*)w;   w += (size_t)(NB2 + 8) * 4;
  int* bbase   = (int*)w;   w += (size_t)(NB2 + 1) * 4;
  float* bmax  = (float*)w; w += 256 * 4;
  float* bsumF = (float*)w; w += 256 * 4;
  float* gred  = (float*)w; w += 2 * 4;
  unsigned short* w1th  = (unsigned short*)w; w += (size_t)64 * 64 * 2;
  unsigned short* w1tl  = (unsigned short*)w; w += (size_t)64 * 64 * 2;
  unsigned short* w0cth = (unsigned short*)w; w += (size_t)128 * 128 * 2;
  unsigned short* w0ctl = (unsigned short*)w; w += (size_t)128 * 128 * 2;

  unsigned short* eid16 = (unsigned short*)eid;

  unsigned* ebin = (unsigned*)regB;
  unsigned short* hb0h = (unsigned short*)regB;
  unsigned short* hb0l = hb0h + (size_t)N_NODES * D;
  unsigned short* xh   = (unsigned short*)regC;
  unsigned short* xl   = xh + (size_t)N_NODES * D;
  unsigned short* hb1h = (unsigned short*)regC;
  unsigned short* hb1l = hb1h + (size_t)N_NODES * D;
  unsigned short* agh = (unsigned short*)regA;
  unsigned short* agl = agh + (size_t)N_NODES * D;
  unsigned short* pbh = (unsigned short*)regA;
  unsigned short* pbl = pbh + (size_t)N_NODES * D;

  unsigned short* bth0 = (unsigned short*)cnt;
  unsigned short* btl0 = bth0 + 128 * 256;
  unsigned short* bth1 = (unsigned short*)cur;
  unsigned short* btl1 = bth1 + 128 * 256;

  // ---- CSR build ----
  hipMemsetAsync(gcnt, 0, (size_t)NB2 * 4, stream);
  k_bin   <<<NTILE, 256, 0, stream>>>(src, dst, gcnt, ebin, N_EDGES);
  k_bscan2<<<1, 256, 0, stream>>>(gcnt, bbase, rowptr);
  k_bfin  <<<NB2, 256, 0, stream>>>(gcnt, bbase, ebin, eid16, rowptr, N_NODES);

  // ---- fused conversions ----
  int PREPB = 448 + (N_NODES * D / 8 + 255) / 256;
  k_prep<<<PREPB, 256, 0, stream>>>(ws0, wn0, ws1, wn1, mw0, mw1, x,
      bth0, btl0, bth1, btl1, w1th, w1tl, w0cth, w0ctl, xh, xl);

  int GB = (N_NODES + 63) / 64;     // 782
  int AB = (N_NODES + 31) / 32;     // 1563 (fully co-resident)
  k_agg_q<<<AB, 256, 0, stream>>>(xh, rowptr, eid16, agh, agl, N_NODES);
  k_sage_mfma<<<GB, 256, 0, stream>>>(xh, xl, agh, agl, bth0, btl0,
                                      b0, g0, be0, rm0, rv0, hb0h, hb0l, N_NODES, 0);
  k_agg_q<<<AB, 256, 0, stream>>>(hb0h, rowptr, eid16, agh, agl, N_NODES);
  k_sage_mfma<<<GB, 256, 0, stream>>>(hb0h, hb0l, agh, agl, bth1, btl1,
                                      b1, g1, be1, rm1, rv1, hb1h, hb1l, N_NODES, 1);

  k_pgemm<<<GB, 256, 0, stream>>>(hb1h, hb1l, w0cth, w0ctl, pbh, pbl, N_NODES);

  k_mlp2<<<(N_CAND + 127) / 128, 256, 0, stream>>>(pbh, pbl, cu, cv, cf,
      mw0, mb0, w1th, w1tl, mb1, mw2, mb2, out, N_CAND);

  k_red1<<<256, 256, 0, stream>>>(out, bmax, bsumF, N_CAND);
  k_red2<<<1, 256, 0, stream>>>(bmax, bsumF, gred, 256);
  k_red3<<<(N_CAND + 255) / 256, 256, 0, stream>>>(out, gred, out + N_CAND, N_CAND);
}

// Round 14
// 210.121 us; speedup vs baseline: 1.1091x; 1.1091x over previous
//
#include <hip/hip_runtime.h>
#include <math.h>

#define N_NODES 50000
#define N_EDGES 800000
#define N_CAND  100000
#define D       128
#define BN_EPS  1e-5f
#define SLOPE   0.01f

// tiled-binning CSR build
#define NB2     196
#define TILE    4096
#define NTILE   196
#define BCAP    4736

typedef __attribute__((ext_vector_type(8))) short bf16x8;
typedef __attribute__((ext_vector_type(4))) float f32x4;

__device__ __forceinline__ float lrelu(float x){ return x >= 0.f ? x : SLOPE * x; }

__device__ __forceinline__ unsigned short f2bf_rn(float f){
  unsigned int u = __float_as_uint(f);
  unsigned int r = u + 0x7FFFu + ((u >> 16) & 1u);
  return (unsigned short)(r >> 16);
}
__device__ __forceinline__ float bf2f(unsigned short h){
  return __uint_as_float(((unsigned int)h) << 16);
}
__device__ __forceinline__ float bfu(unsigned u){ return __uint_as_float(u << 16); }
__device__ __forceinline__ float bfh(unsigned u){ return __uint_as_float(u & 0xffff0000u); }
__device__ __forceinline__ float4 bf4f(ushort4 u){
  return make_float4(__uint_as_float((unsigned)u.x << 16),
                     __uint_as_float((unsigned)u.y << 16),
                     __uint_as_float((unsigned)u.z << 16),
                     __uint_as_float((unsigned)u.w << 16));
}

__device__ __forceinline__ unsigned pk_bf16(float a, float b){
  unsigned r;
  asm("v_cvt_pk_bf16_f32 %0, %1, %2" : "=v"(r) : "v"(a), "v"(b));
  return r;
}
__device__ __forceinline__ void split2(float a, float b, unsigned &h, unsigned &l){
  h = pk_bf16(a, b);
  float ra = a - __uint_as_float(h << 16);
  float rb = b - __uint_as_float(h & 0xffff0000u);
  l = pk_bf16(ra, rb);
}

// ---------------- CSR build: LDS-staged tiled binning ----------------
__global__ __launch_bounds__(256) void k_bin(const int* __restrict__ src, const int* __restrict__ dst,
                                             int* __restrict__ gcnt, unsigned* __restrict__ ebin, int E){
  __shared__ unsigned stage[TILE];
  __shared__ int hist[256], lscan[256], lex[256], lcur[256], gbase[256];
  __shared__ int stot;
  int t = threadIdx.x;
  int e0 = blockIdx.x * TILE;

  hist[t] = 0;
  __syncthreads();

  unsigned pk[16]; int bk[16]; bool ok[16];
  #pragma unroll
  for (int j = 0; j < 16; ++j){
    int i = e0 + j * 256 + t;
    ok[j] = (i < E);
    if (ok[j]){
      int d = dst[i];
      pk[j] = ((unsigned)d << 16) | (unsigned)src[i];
      bk[j] = d >> 8;
      atomicAdd(&hist[bk[j]], 1);
    }
  }
  __syncthreads();

  lscan[t] = hist[t];
  __syncthreads();
  for (int off = 1; off < 256; off <<= 1){
    int v = (t >= off) ? lscan[t - off] : 0;
    __syncthreads();
    lscan[t] += v;
    __syncthreads();
  }
  int ex = lscan[t] - hist[t];
  lex[t]  = ex;
  lcur[t] = ex;
  if (t < NB2) gbase[t] = hist[t] ? atomicAdd(&gcnt[t], hist[t]) : 0;
  if (t == 255) stot = lscan[255];
  __syncthreads();

  #pragma unroll
  for (int j = 0; j < 16; ++j){
    if (ok[j]){
      int p = atomicAdd(&lcur[bk[j]], 1);
      stage[p] = pk[j];
    }
  }
  __syncthreads();

  int tot = stot;
  for (int i = t; i < tot; i += 256){
    unsigned e = stage[i];
    int b = (int)(e >> 24);
    ebin[(size_t)b * BCAP + gbase[b] + (i - lex[b])] = e;
  }
}

__global__ __launch_bounds__(256) void k_bscan2(const int* __restrict__ gcnt, int* __restrict__ bbase,
                                                int* __restrict__ rowptr){
  __shared__ int sd[256];
  int t = threadIdx.x;
  int v = (t < NB2) ? gcnt[t] : 0;
  sd[t] = v; __syncthreads();
  for (int off = 1; off < 256; off <<= 1){
    int a = (t >= off) ? sd[t - off] : 0;
    __syncthreads();
    sd[t] += a; __syncthreads();
  }
  if (t < NB2) bbase[t] = sd[t] - v;
  if (t == NB2 - 1) rowptr[N_NODES] = sd[t];
}

__global__ __launch_bounds__(256) void k_bfin(const int* __restrict__ gcnt, const int* __restrict__ bbase,
                                              const unsigned* __restrict__ ebin,
                                              unsigned short* __restrict__ eid16,
                                              int* __restrict__ rowptr, int n){
  __shared__ int hist[256], lb[256], lcur[256];
  int t = threadIdx.x, b = blockIdx.x;
  int cb   = gcnt[b];
  int base = bbase[b];
  const unsigned* eb = &ebin[(size_t)b * BCAP];
  hist[t] = 0;
  __syncthreads();
  for (int idx = t; idx < cb; idx += 256) atomicAdd(&hist[(eb[idx] >> 16) & 255], 1);
  __syncthreads();
  lb[t] = hist[t];
  __syncthreads();
  for (int off = 1; off < 256; off <<= 1){
    int v = (t >= off) ? lb[t - off] : 0;
    __syncthreads();
    lb[t] += v; __syncthreads();
  }
  int ex = lb[t] - hist[t];
  lcur[t] = ex;
  int node = (b << 8) + t;
  if (node < n) rowptr[node] = base + ex;
  __syncthreads();
  for (int idx = t; idx < cb; idx += 256){
    unsigned e = eb[idx];
    int p = atomicAdd(&lcur[(e >> 16) & 255], 1);
    eid16[base + p] = (unsigned short)(e & 0xffffu);
  }
}

// ---------------- fused prep: all weight/input conversions in ONE kernel ----------------
__global__ __launch_bounds__(256) void k_prep(
    const float* __restrict__ ws0, const float* __restrict__ wn0,
    const float* __restrict__ ws1, const float* __restrict__ wn1,
    const float* __restrict__ mw0, const float* __restrict__ mw1,
    const float* __restrict__ X,
    unsigned short* __restrict__ bth0, unsigned short* __restrict__ btl0,
    unsigned short* __restrict__ bth1, unsigned short* __restrict__ btl1,
    unsigned short* __restrict__ w1th, unsigned short* __restrict__ w1tl,
    unsigned short* __restrict__ w0cth, unsigned short* __restrict__ w0ctl,
    unsigned short* __restrict__ XH, unsigned short* __restrict__ XL)
{
  int b = blockIdx.x, t = threadIdx.x;
  if (b < 256){
    int col = b & 127;
    const float* wsp = (b < 128) ? ws0 : ws1;
    const float* wnp = (b < 128) ? wn0 : wn1;
    unsigned short* th = (b < 128) ? bth0 : bth1;
    unsigned short* tl = (b < 128) ? btl0 : btl1;
    float v = (t < 128) ? wsp[t * D + col] : wnp[(t - 128) * D + col];
    unsigned short hi = f2bf_rn(v);
    th[col * 256 + t] = hi;
    tl[col * 256 + t] = f2bf_rn(v - bf2f(hi));
  } else if (b < 320){
    if (t < 64){
      int col = b - 256;
      float v = mw1[t * 64 + col];
      unsigned short hi = f2bf_rn(v);
      w1th[col * 64 + t] = hi;
      w1tl[col * 64 + t] = f2bf_rn(v - bf2f(hi));
    }
  } else if (b < 448){
    if (t < 128){
      int col = b - 320;
      float v = (col < 64) ? mw0[t * 64 + col] : mw0[(128 + t) * 64 + (col - 64)];
      unsigned short hi = f2bf_rn(v);
      w0cth[col * 128 + t] = hi;
      w0ctl[col * 128 + t] = f2bf_rn(v - bf2f(hi));
    }
  } else {
    int i = (b - 448) * 256 + t;            // 8 floats per thread
    if (i < N_NODES * D / 8){
      const float4* xp = reinterpret_cast<const float4*>(&X[(size_t)i * 8]);
      float4 v0 = xp[0], v1 = xp[1];
      uint4 h, l;
      split2(v0.x, v0.y, h.x, l.x);
      split2(v0.z, v0.w, h.y, l.y);
      split2(v1.x, v1.y, h.z, l.z);
      split2(v1.z, v1.w, h.w, l.w);
      *reinterpret_cast<uint4*>(&XH[(size_t)i * 8]) = h;
      *reinterpret_cast<uint4*>(&XL[(size_t)i * 8]) = l;
    }
  }
}

// ---------------- mean aggregation: bf16 gather, split-bf16 output ----------------
// (round-12 proven form: 32 lanes/node, full 256B row per edge, x4 unroll;
// round-13's D-quarter blocking REGRESSED 28->45us: same line traffic,
// blocks drift out of quarter-phase so L2 never captures the working set,
// and 8-lane groups halved loads-in-flight.)
__global__ __launch_bounds__(256) void k_agg_bf(const unsigned short* __restrict__ XB,
                                                const int* __restrict__ rowptr, const unsigned short* __restrict__ eid,
                                                unsigned short* __restrict__ AGH, unsigned short* __restrict__ AGL,
                                                int n){
  int g = blockIdx.x * 8 + (threadIdx.x >> 5);   // node
  int l = threadIdx.x & 31;                      // 4-bf16 chunk
  if (g >= n) return;
  int e0 = rowptr[g], e1 = rowptr[g + 1];
  float4 a0 = make_float4(0.f,0.f,0.f,0.f);
  float4 a1 = make_float4(0.f,0.f,0.f,0.f);
  float4 a2 = make_float4(0.f,0.f,0.f,0.f);
  float4 a3 = make_float4(0.f,0.f,0.f,0.f);
  int e = e0;
  for (; e + 4 <= e1; e += 4){
    int s0 = eid[e], s1 = eid[e + 1], s2 = eid[e + 2], s3 = eid[e + 3];
    ushort4 u0 = *reinterpret_cast<const ushort4*>(&XB[(size_t)s0 * D + l * 4]);
    ushort4 u1 = *reinterpret_cast<const ushort4*>(&XB[(size_t)s1 * D + l * 4]);
    ushort4 u2 = *reinterpret_cast<const ushort4*>(&XB[(size_t)s2 * D + l * 4]);
    ushort4 u3 = *reinterpret_cast<const ushort4*>(&XB[(size_t)s3 * D + l * 4]);
    float4 f0 = bf4f(u0), f1 = bf4f(u1), f2 = bf4f(u2), f3 = bf4f(u3);
    a0.x += f0.x; a0.y += f0.y; a0.z += f0.z; a0.w += f0.w;
    a1.x += f1.x; a1.y += f1.y; a1.z += f1.z; a1.w += f1.w;
    a2.x += f2.x; a2.y += f2.y; a2.z += f2.z; a2.w += f2.w;
    a3.x += f3.x; a3.y += f3.y; a3.z += f3.z; a3.w += f3.w;
  }
  for (; e < e1; ++e){
    int s0 = eid[e];
    ushort4 u0 = *reinterpret_cast<const ushort4*>(&XB[(size_t)s0 * D + l * 4]);
    float4 f0 = bf4f(u0);
    a0.x += f0.x; a0.y += f0.y; a0.z += f0.z; a0.w += f0.w;
  }
  float sc = 1.f / fmaxf((float)(e1 - e0), 1.f);
  float ox = (a0.x + a1.x + a2.x + a3.x) * sc;
  float oy = (a0.y + a1.y + a2.y + a3.y) * sc;
  float oz = (a0.z + a1.z + a2.z + a3.z) * sc;
  float ow = (a0.w + a1.w + a2.w + a3.w) * sc;
  uint2 h, lo_;
  split2(ox, oy, h.x, lo_.x);
  split2(oz, ow, h.y, lo_.y);
  *reinterpret_cast<uint2*>(&AGH[(size_t)g * D + l * 4]) = h;
  *reinterpret_cast<uint2*>(&AGL[(size_t)g * D + l * 4]) = lo_;
}

// ---------------- SAGE layer via split-bf16 MFMA (all-pre-split inputs) ----------------
__global__ __launch_bounds__(256) void k_sage_mfma(
    const unsigned short* __restrict__ A0H, const unsigned short* __restrict__ A0L,
    const unsigned short* __restrict__ A1H, const unsigned short* __restrict__ A1L,
    const unsigned short* __restrict__ BTH, const unsigned short* __restrict__ BTL,
    const float* __restrict__ Bb, const float* __restrict__ GM, const float* __restrict__ BT,
    const float* __restrict__ RM, const float* __restrict__ RV,
    unsigned short* __restrict__ HBH, unsigned short* __restrict__ HBL,
    int n, int donan)
{
  __shared__ unsigned short Ah[64 * 40];
  __shared__ unsigned short Al[64 * 40];
  __shared__ unsigned short Bh[128 * 40];
  __shared__ unsigned short Bl[128 * 40];

  int t  = threadIdx.x;
  int l  = t & 63;
  int wv = t >> 6;
  int lm = l & 15;
  int lk = l >> 4;
  int node0 = blockIdx.x * 64;

  f32x4 acc[8];
  #pragma unroll
  for (int f = 0; f < 8; ++f) acc[f] = (f32x4){0.f, 0.f, 0.f, 0.f};

  for (int step = 0; step < 8; ++step){
    int k0 = step * 32;
    const unsigned short* srcH = (step < 4) ? A0H : A1H;
    const unsigned short* srcL = (step < 4) ? A0L : A1L;
    int koff = (step < 4) ? k0 : (k0 - 128);

    __syncthreads();
    {
      int row = t >> 2, q = t & 3;
      int node = min(node0 + row, n - 1);
      *reinterpret_cast<uint4*>(&Ah[row * 40 + q * 8]) =
          *reinterpret_cast<const uint4*>(&srcH[(size_t)node * D + koff + q * 8]);
      *reinterpret_cast<uint4*>(&Al[row * 40 + q * 8]) =
          *reinterpret_cast<const uint4*>(&srcL[(size_t)node * D + koff + q * 8]);
    }
    #pragma unroll
    for (int i = 0; i < 2; ++i){
      int c   = t + i * 256;
      int col = c >> 2, q = c & 3;
      *reinterpret_cast<uint4*>(&Bh[col * 40 + q * 8]) =
          *reinterpret_cast<const uint4*>(&BTH[col * 256 + k0 + q * 8]);
      *reinterpret_cast<uint4*>(&Bl[col * 40 + q * 8]) =
          *reinterpret_cast<const uint4*>(&BTL[col * 256 + k0 + q * 8]);
    }
    __syncthreads();

    bf16x8 afh = *reinterpret_cast<const bf16x8*>(&Ah[(wv * 16 + lm) * 40 + lk * 8]);
    bf16x8 afl = *reinterpret_cast<const bf16x8*>(&Al[(wv * 16 + lm) * 40 + lk * 8]);
    #pragma unroll
    for (int f = 0; f < 8; ++f){
      bf16x8 bfh = *reinterpret_cast<const bf16x8*>(&Bh[(f * 16 + lm) * 40 + lk * 8]);
      bf16x8 bfl = *reinterpret_cast<const bf16x8*>(&Bl[(f * 16 + lm) * 40 + lk * 8]);
      acc[f] = __builtin_amdgcn_mfma_f32_16x16x32_bf16(afh, bfh, acc[f], 0, 0, 0);
      acc[f] = __builtin_amdgcn_mfma_f32_16x16x32_bf16(afl, bfh, acc[f], 0, 0, 0);
      acc[f] = __builtin_amdgcn_mfma_f32_16x16x32_bf16(afh, bfl, acc[f], 0, 0, 0);
    }
  }

  #pragma unroll
  for (int f = 0; f < 8; ++f){
    int col = f * 16 + lm;
    float s  = GM[col] * rsqrtf(RV[col] + BN_EPS);
    float cj = (Bb[col] - RM[col]) * s + BT[col];
    #pragma unroll
    for (int r = 0; r < 4; ++r){
      int node = node0 + wv * 16 + lk * 4 + r;
      if (node < n){
        float v = lrelu(acc[f][r] * s + cj);
        if (donan && (v != v)) v = 1e-14f;
        unsigned short h16 = f2bf_rn(v);
        HBH[(size_t)node * D + col] = h16;
        HBL[(size_t)node * D + col] = f2bf_rn(v - bf2f(h16));
      }
    }
  }
}

// ---------------- P = h1 @ [W0u | W0v]  (dense GEMM, pre-split in/out) ----------------
__global__ __launch_bounds__(256) void k_pgemm(
    const unsigned short* __restrict__ HH, const unsigned short* __restrict__ HL,
    const unsigned short* __restrict__ WCH, const unsigned short* __restrict__ WCL,
    unsigned short* __restrict__ PH, unsigned short* __restrict__ PL, int n)
{
  __shared__ unsigned short Ah[64 * 40];
  __shared__ unsigned short Al[64 * 40];
  __shared__ unsigned short Bh[128 * 40];
  __shared__ unsigned short Bl[128 * 40];

  int t  = threadIdx.x;
  int l  = t & 63;
  int wv = t >> 6;
  int lm = l & 15;
  int lk = l >> 4;
  int node0 = blockIdx.x * 64;

  f32x4 acc[8];
  #pragma unroll
  for (int f = 0; f < 8; ++f) acc[f] = (f32x4){0.f, 0.f, 0.f, 0.f};

  for (int step = 0; step < 4; ++step){
    int k0 = step * 32;
    __syncthreads();
    {
      int row = t >> 2, q = t & 3;
      int node = min(node0 + row, n - 1);
      *reinterpret_cast<uint4*>(&Ah[row * 40 + q * 8]) =
          *reinterpret_cast<const uint4*>(&HH[(size_t)node * D + k0 + q * 8]);
      *reinterpret_cast<uint4*>(&Al[row * 40 + q * 8]) =
          *reinterpret_cast<const uint4*>(&HL[(size_t)node * D + k0 + q * 8]);
    }
    #pragma unroll
    for (int i = 0; i < 2; ++i){
      int c = t + i * 256;
      int col = c >> 2, q = c & 3;
      *reinterpret_cast<uint4*>(&Bh[col * 40 + q * 8]) =
          *reinterpret_cast<const uint4*>(&WCH[col * 128 + k0 + q * 8]);
      *reinterpret_cast<uint4*>(&Bl[col * 40 + q * 8]) =
          *reinterpret_cast<const uint4*>(&WCL[col * 128 + k0 + q * 8]);
    }
    __syncthreads();

    bf16x8 afh = *reinterpret_cast<const bf16x8*>(&Ah[(wv * 16 + lm) * 40 + lk * 8]);
    bf16x8 afl = *reinterpret_cast<const bf16x8*>(&Al[(wv * 16 + lm) * 40 + lk * 8]);
    #pragma unroll
    for (int f = 0; f < 8; ++f){
      bf16x8 bfh = *reinterpret_cast<const bf16x8*>(&Bh[(f * 16 + lm) * 40 + lk * 8]);
      bf16x8 bfl = *reinterpret_cast<const bf16x8*>(&Bl[(f * 16 + lm) * 40 + lk * 8]);
      acc[f] = __builtin_amdgcn_mfma_f32_16x16x32_bf16(afh, bfh, acc[f], 0, 0, 0);
      acc[f] = __builtin_amdgcn_mfma_f32_16x16x32_bf16(afl, bfh, acc[f], 0, 0, 0);
      acc[f] = __builtin_amdgcn_mfma_f32_16x16x32_bf16(afh, bfl, acc[f], 0, 0, 0);
    }
  }

  #pragma unroll
  for (int f = 0; f < 8; ++f){
    int col = f * 16 + lm;
    #pragma unroll
    for (int r = 0; r < 4; ++r){
      int node = node0 + wv * 16 + lk * 4 + r;
      if (node < n){
        float v = acc[f][r];
        unsigned short h16 = f2bf_rn(v);
        PH[(size_t)node * D + col] = h16;
        PL[(size_t)node * D + col] = f2bf_rn(v - bf2f(h16));
      }
    }
  }
}

__device__ __forceinline__ void proc2(unsigned uh, unsigned ul, unsigned vh, unsigned vl,
                                      float wfa, float wfb, float b0a, float b0b, float cfv,
                                      unsigned &ho, unsigned &lo_){
  float z0 = lrelu(bfu(uh) + bfu(ul) + bfu(vh) + bfu(vl) + cfv * wfa + b0a);
  float z1 = lrelu(bfh(uh) + bfh(ul) + bfh(vh) + bfh(vl) + cfv * wfb + b0b);
  split2(z0, z1, ho, lo_);
}

// ---------------- candidate MLP tail: gather P + L2 + L3 ----------------
__global__ __launch_bounds__(256) void k_mlp2(
    const unsigned short* __restrict__ PH, const unsigned short* __restrict__ PL,
    const int* __restrict__ cu, const int* __restrict__ cv, const float* __restrict__ cf,
    const float* __restrict__ mw0, const float* __restrict__ mb0,
    const unsigned short* __restrict__ W1H, const unsigned short* __restrict__ W1L,
    const float* __restrict__ mb1, const float* __restrict__ mw2, const float* __restrict__ mb2,
    float* __restrict__ y, int C)
{
  __shared__ unsigned short zh[4][32 * 72];
  __shared__ unsigned short zl[4][32 * 72];
  __shared__ float bw[64], ww[64];

  int t = threadIdx.x;
  int wv = t >> 6, l = t & 63, lm = l & 15, lk = l >> 4;
  int cl = l & 31, hsel = l >> 5;
  int candbase = blockIdx.x * 128 + wv * 32;

  if (t < 64){ bw[t] = mb0[t]; ww[t] = mw0[256 * 64 + t]; }
  __syncthreads();

  int cc = min(candbase + cl, C - 1);
  int nu = cu[cc], nv = cv[cc];
  float cfv = cf[cc];

  const uint4* puh = reinterpret_cast<const uint4*>(&PH[(size_t)nu * D + hsel * 32]);
  const uint4* pul = reinterpret_cast<const uint4*>(&PL[(size_t)nu * D + hsel * 32]);
  const uint4* pvh = reinterpret_cast<const uint4*>(&PH[(size_t)nv * D + 64 + hsel * 32]);
  const uint4* pvl = reinterpret_cast<const uint4*>(&PL[(size_t)nv * D + 64 + hsel * 32]);
  uint4 uh0 = puh[0], uh1 = puh[1], uh2 = puh[2], uh3 = puh[3];
  uint4 ul0 = pul[0], ul1 = pul[1], ul2 = pul[2], ul3 = pul[3];
  uint4 vh0 = pvh[0], vh1 = pvh[1], vh2 = pvh[2], vh3 = pvh[3];
  uint4 vl0 = pvl[0], vl1 = pvl[1], vl2 = pvl[2], vl3 = pvl[3];

  int colb = hsel * 32;
  unsigned short* zhr = &zh[wv][cl * 72];
  unsigned short* zlr = &zl[wv][cl * 72];
  #define PROC_W(UH, UL, VH, VL, CO) { \
    unsigned ho, lo_; \
    proc2(UH, UL, VH, VL, ww[colb + (CO)], ww[colb + (CO) + 1], bw[colb + (CO)], bw[colb + (CO) + 1], cfv, ho, lo_); \
    *reinterpret_cast<unsigned*>(&zhr[colb + (CO)]) = ho; \
    *reinterpret_cast<unsigned*>(&zlr[colb + (CO)]) = lo_; }
  PROC_W(uh0.x, ul0.x, vh0.x, vl0.x, 0)  PROC_W(uh0.y, ul0.y, vh0.y, vl0.y, 2)
  PROC_W(uh0.z, ul0.z, vh0.z, vl0.z, 4)  PROC_W(uh0.w, ul0.w, vh0.w, vl0.w, 6)
  PROC_W(uh1.x, ul1.x, vh1.x, vl1.x, 8)  PROC_W(uh1.y, ul1.y, vh1.y, vl1.y, 10)
  PROC_W(uh1.z, ul1.z, vh1.z, vl1.z, 12) PROC_W(uh1.w, ul1.w, vh1.w, vl1.w, 14)
  PROC_W(uh2.x, ul2.x, vh2.x, vl2.x, 16) PROC_W(uh2.y, ul2.y, vh2.y, vl2.y, 18)
  PROC_W(uh2.z, ul2.z, vh2.z, vl2.z, 20) PROC_W(uh2.w, ul2.w, vh2.w, vl2.w, 22)
  PROC_W(uh3.x, ul3.x, vh3.x, vl3.x, 24) PROC_W(uh3.y, ul3.y, vh3.y, vl3.y, 26)
  PROC_W(uh3.z, ul3.z, vh3.z, vl3.z, 28) PROC_W(uh3.w, ul3.w, vh3.w, vl3.w, 30)
  #undef PROC_W

  int kbase = lk * 8;
  f32x4 a2[2][4];
  #pragma unroll
  for (int m = 0; m < 2; ++m)
    #pragma unroll
    for (int f = 0; f < 4; ++f) a2[m][f] = (f32x4){0.f, 0.f, 0.f, 0.f};

  #pragma unroll
  for (int s2 = 0; s2 < 2; ++s2){
    int kk = s2 * 32 + kbase;
    bf16x8 azh0 = *reinterpret_cast<const bf16x8*>(&zh[wv][(0 * 16 + lm) * 72 + kk]);
    bf16x8 azl0 = *reinterpret_cast<const bf16x8*>(&zl[wv][(0 * 16 + lm) * 72 + kk]);
    bf16x8 azh1 = *reinterpret_cast<const bf16x8*>(&zh[wv][(1 * 16 + lm) * 72 + kk]);
    bf16x8 azl1 = *reinterpret_cast<const bf16x8*>(&zl[wv][(1 * 16 + lm) * 72 + kk]);
    #pragma unroll
    for (int f = 0; f < 4; ++f){
      int col = f * 16 + lm;
      bf16x8 bh = *reinterpret_cast<const bf16x8*>(&W1H[(size_t)col * 64 + kk]);
      bf16x8 bl = *reinterpret_cast<const bf16x8*>(&W1L[(size_t)col * 64 + kk]);
      a2[0][f] = __builtin_amdgcn_mfma_f32_16x16x32_bf16(azh0, bh, a2[0][f], 0, 0, 0);
      a2[0][f] = __builtin_amdgcn_mfma_f32_16x16x32_bf16(azl0, bh, a2[0][f], 0, 0, 0);
      a2[0][f] = __builtin_amdgcn_mfma_f32_16x16x32_bf16(azh0, bl, a2[0][f], 0, 0, 0);
      a2[1][f] = __builtin_amdgcn_mfma_f32_16x16x32_bf16(azh1, bh, a2[1][f], 0, 0, 0);
      a2[1][f] = __builtin_amdgcn_mfma_f32_16x16x32_bf16(azl1, bh, a2[1][f], 0, 0, 0);
      a2[1][f] = __builtin_amdgcn_mfma_f32_16x16x32_bf16(azh1, bl, a2[1][f], 0, 0, 0);
    }
  }

  float p00 = 0.f, p01 = 0.f, p02 = 0.f, p03 = 0.f;
  float p10 = 0.f, p11 = 0.f, p12 = 0.f, p13 = 0.f;
  #pragma unroll
  for (int f = 0; f < 4; ++f){
    int col = f * 16 + lm;
    float b1v = mb1[col];
    float w2v = mw2[col];
    p00 = fmaf(lrelu(a2[0][f][0] + b1v), w2v, p00);
    p01 = fmaf(lrelu(a2[0][f][1] + b1v), w2v, p01);
    p02 = fmaf(lrelu(a2[0][f][2] + b1v), w2v, p02);
    p03 = fmaf(lrelu(a2[0][f][3] + b1v), w2v, p03);
    p10 = fmaf(lrelu(a2[1][f][0] + b1v), w2v, p10);
    p11 = fmaf(lrelu(a2[1][f][1] + b1v), w2v, p11);
    p12 = fmaf(lrelu(a2[1][f][2] + b1v), w2v, p12);
    p13 = fmaf(lrelu(a2[1][f][3] + b1v), w2v, p13);
  }
  #pragma unroll
  for (int off = 1; off < 16; off <<= 1){
    p00 += __shfl_xor(p00, off); p01 += __shfl_xor(p01, off);
    p02 += __shfl_xor(p02, off); p03 += __shfl_xor(p03, off);
    p10 += __shfl_xor(p10, off); p11 += __shfl_xor(p11, off);
    p12 += __shfl_xor(p12, off); p13 += __shfl_xor(p13, off);
  }
  if (lm == 0){
    float b2 = mb2[0];
    int base0 = candbase + lk * 4;
    int base1 = candbase + 16 + lk * 4;
    if (base0 + 0 < C) y[base0 + 0] = p00 + b2;
    if (base0 + 1 < C) y[base0 + 1] = p01 + b2;
    if (base0 + 2 < C) y[base0 + 2] = p02 + b2;
    if (base0 + 3 < C) y[base0 + 3] = p03 + b2;
    if (base1 + 0 < C) y[base1 + 0] = p10 + b2;
    if (base1 + 1 < C) y[base1 + 1] = p11 + b2;
    if (base1 + 2 < C) y[base1 + 2] = p12 + b2;
    if (base1 + 3 < C) y[base1 + 3] = p13 + b2;
  }
}

// ---------------- softmax over C logits ----------------
__global__ __launch_bounds__(256) void k_red1(const float* __restrict__ y,
                                              float* __restrict__ bmax, float* __restrict__ bsum, int C){
  __shared__ float sm[4];
  __shared__ float ss[4];
  int t = threadIdx.x;
  float m = -3.4e38f;
  for (int i = blockIdx.x * 256 + t; i < C; i += gridDim.x * 256) m = fmaxf(m, y[i]);
  for (int o = 32; o; o >>= 1) m = fmaxf(m, __shfl_xor(m, o));
  if ((t & 63) == 0) sm[t >> 6] = m;
  __syncthreads();
  float bm = fmaxf(fmaxf(sm[0], sm[1]), fmaxf(sm[2], sm[3]));
  float s = 0.f;
  for (int i = blockIdx.x * 256 + t; i < C; i += gridDim.x * 256) s += expf(y[i] - bm);
  for (int o = 32; o; o >>= 1) s += __shfl_xor(s, o);
  if ((t & 63) == 0) ss[t >> 6] = s;
  __syncthreads();
  if (t == 0){ bmax[blockIdx.x] = bm; bsum[blockIdx.x] = ss[0] + ss[1] + ss[2] + ss[3]; }
}

__global__ __launch_bounds__(256) void k_red2(const float* __restrict__ bmax, const float* __restrict__ bsum,
                                              float* __restrict__ g, int nb){
  __shared__ float sm[4];
  __shared__ float ss[4];
  int t = threadIdx.x;
  float m0 = (t < nb) ? bmax[t] : -3.4e38f;
  float m = m0;
  for (int o = 32; o; o >>= 1) m = fmaxf(m, __shfl_xor(m, o));
  if ((t & 63) == 0) sm[t >> 6] = m;
  __syncthreads();
  float gm = fmaxf(fmaxf(sm[0], sm[1]), fmaxf(sm[2], sm[3]));
  float s = (t < nb) ? bsum[t] * expf(m0 - gm) : 0.f;
  for (int o = 32; o; o >>= 1) s += __shfl_xor(s, o);
  if ((t & 63) == 0) ss[t >> 6] = s;
  __syncthreads();
  if (t == 0){ g[0] = gm; g[1] = 1.f / (ss[0] + ss[1] + ss[2] + ss[3]); }
}

__global__ __launch_bounds__(256) void k_red3(const float* __restrict__ y, const float* __restrict__ g,
                                              float* __restrict__ out, int C){
  int i = blockIdx.x * 256 + threadIdx.x;
  if (i < C) out[i] = expf(y[i] - g[0]) * g[1];
}

extern "C" void kernel_launch(void* const* d_in, const int* in_sizes, int n_in,
                              void* d_out, int out_size, void* d_ws, size_t ws_size,
                              hipStream_t stream)
{
  const float* x   = (const float*)d_in[0];
  const int*   src = (const int*)  d_in[1];
  const int*   dst = (const int*)  d_in[2];
  const int*   cu  = (const int*)  d_in[3];
  const int*   cv  = (const int*)  d_in[4];
  const float* cf  = (const float*)d_in[5];
  const float* ws0 = (const float*)d_in[6];
  const float* wn0 = (const float*)d_in[7];
  const float* b0  = (const float*)d_in[8];
  const float* g0  = (const float*)d_in[9];
  const float* be0 = (const float*)d_in[10];
  const float* rm0 = (const float*)d_in[11];
  const float* rv0 = (const float*)d_in[12];
  const float* ws1 = (const float*)d_in[13];
  const float* wn1 = (const float*)d_in[14];
  const float* b1  = (const float*)d_in[15];
  const float* g1  = (const float*)d_in[16];
  const float* be1 = (const float*)d_in[17];
  const float* rm1 = (const float*)d_in[18];
  const float* rv1 = (const float*)d_in[19];
  const float* mw0 = (const float*)d_in[20];
  const float* mb0 = (const float*)d_in[21];
  const float* mw1 = (const float*)d_in[22];
  const float* mb1 = (const float*)d_in[23];
  const float* mw2 = (const float*)d_in[24];
  const float* mb2 = (const float*)d_in[25];

  float* out = (float*)d_out;   // [C] y then [C] softmax

  char* w = (char*)d_ws;
  char* regA = w; w += (size_t)N_NODES * D * 4;   // agh/agl -> later ph/pl
  char* regB = w; w += (size_t)N_NODES * D * 4;   // ebin -> hb0h/hb0l
  char* regC = w; w += (size_t)N_NODES * D * 4;   // xh/xl -> hb1h/hb1l
  int* cnt     = (int*)w;   w += (size_t)N_NODES * 4;          // -> SAGE weights L0
  int* rowptr  = (int*)w;   w += (size_t)(N_NODES + 1) * 4;
  int* cur     = (int*)w;   w += (size_t)N_NODES * 4;          // -> SAGE weights L1
  int* eid     = (int*)w;   w += (size_t)N_EDGES * 4;          // holds eid16
  int* gcnt    = (int*)w;   w += (size_t)(NB2 + 8) * 4;
  int* bbase   = (int*)w;   w += (size_t)(NB2 + 1) * 4;
  float* bmax  = (float*)w; w += 256 * 4;
  float* bsumF = (float*)w; w += 256 * 4;
  float* gred  = (float*)w; w += 2 * 4;
  unsigned short* w1th  = (unsigned short*)w; w += (size_t)64 * 64 * 2;
  unsigned short* w1tl  = (unsigned short*)w; w += (size_t)64 * 64 * 2;
  unsigned short* w0cth = (unsigned short*)w; w += (size_t)128 * 128 * 2;
  unsigned short* w0ctl = (unsigned short*)w; w += (size_t)128 * 128 * 2;

  unsigned short* eid16 = (unsigned short*)eid;

  unsigned* ebin = (unsigned*)regB;
  unsigned short* hb0h = (unsigned short*)regB;
  unsigned short* hb0l = hb0h + (size_t)N_NODES * D;
  unsigned short* xh   = (unsigned short*)regC;
  unsigned short* xl   = xh + (size_t)N_NODES * D;
  unsigned short* hb1h = (unsigned short*)regC;
  unsigned short* hb1l = hb1h + (size_t)N_NODES * D;
  unsigned short* agh = (unsigned short*)regA;
  unsigned short* agl = agh + (size_t)N_NODES * D;
  unsigned short* pbh = (unsigned short*)regA;
  unsigned short* pbl = pbh + (size_t)N_NODES * D;

  unsigned short* bth0 = (unsigned short*)cnt;
  unsigned short* btl0 = bth0 + 128 * 256;
  unsigned short* bth1 = (unsigned short*)cur;
  unsigned short* btl1 = bth1 + 128 * 256;

  // ---- CSR build ----
  hipMemsetAsync(gcnt, 0, (size_t)NB2 * 4, stream);
  k_bin   <<<NTILE, 256, 0, stream>>>(src, dst, gcnt, ebin, N_EDGES);
  k_bscan2<<<1, 256, 0, stream>>>(gcnt, bbase, rowptr);
  k_bfin  <<<NB2, 256, 0, stream>>>(gcnt, bbase, ebin, eid16, rowptr, N_NODES);

  // ---- fused conversions ----
  int PREPB = 448 + (N_NODES * D / 8 + 255) / 256;
  k_prep<<<PREPB, 256, 0, stream>>>(ws0, wn0, ws1, wn1, mw0, mw1, x,
      bth0, btl0, bth1, btl1, w1th, w1tl, w0cth, w0ctl, xh, xl);

  int GB = (N_NODES + 63) / 64;     // 782
  k_agg_bf<<<(N_NODES + 7) / 8, 256, 0, stream>>>(xh, rowptr, eid16, agh, agl, N_NODES);
  k_sage_mfma<<<GB, 256, 0, stream>>>(xh, xl, agh, agl, bth0, btl0,
                                      b0, g0, be0, rm0, rv0, hb0h, hb0l, N_NODES, 0);
  k_agg_bf<<<(N_NODES + 7) / 8, 256, 0, stream>>>(hb0h, rowptr, eid16, agh, agl, N_NODES);
  k_sage_mfma<<<GB, 256, 0, stream>>>(hb0h, hb0l, agh, agl, bth1, btl1,
                                      b1, g1, be1, rm1, rv1, hb1h, hb1l, N_NODES, 1);

  k_pgemm<<<GB, 256, 0, stream>>>(hb1h, hb1l, w0cth, w0ctl, pbh, pbl, N_NODES);

  k_mlp2<<<(N_CAND + 127) / 128, 256, 0, stream>>>(pbh, pbl, cu, cv, cf,
      mw0, mb0, w1th, w1tl, mb1, mw2, mb2, out, N_CAND);

  k_red1<<<256, 256, 0, stream>>>(out, bmax, bsumF, N_CAND);
  k_red2<<<1, 256, 0, stream>>>(bmax, bsumF, gred, 256);
  k_red3<<<(N_CAND + 255) / 256, 256, 0, stream>>>(out, gred, out + N_CAND, N_CAND);
}